// Round 2
// baseline (415.939 us; speedup 1.0000x reference)
//
#include <hip/hip_runtime.h>
#include <hip/hip_bf16.h>

// Problem constants (B=128, N=8, S=16, DIM=64, H=4, DH=16)
#define B_   128
#define N_   8
#define S_   16
#define DIM_ 64
#define H_   4
#define DH_  16

// dot of a contiguous 64-elem fp32 row with a 64-elem fp32 vector (regs/LDS)
__device__ __forceinline__ float dot_row64f(const float* __restrict__ row,
                                            const float* __restrict__ v) {
    const float4* rp = (const float4*)row;
    float acc = 0.f;
#pragma unroll
    for (int m = 0; m < 16; ++m) {
        float4 u = rp[m];
        acc = fmaf(u.x, v[4 * m + 0], acc);
        acc = fmaf(u.y, v[4 * m + 1], acc);
        acc = fmaf(u.z, v[4 * m + 2], acc);
        acc = fmaf(u.w, v[4 * m + 3], acc);
    }
    return acc;
}

__global__ __launch_bounds__(256) void EntityAggregator_63342177681721_kernel(
    const float* __restrict__ self_e,   // [B][N][64]
    const float* __restrict__ nghu,     // [B][S][64]
    const float* __restrict__ nghe,     // [B][N][S][64]
    const float* __restrict__ user_e,   // [B][64]
    const float* __restrict__ item_e,   // [B][64]
    const float* __restrict__ W_r,      // [B][N][S][64][64]
    const float* __restrict__ W_ui,     // [64][64]
    const float* __restrict__ lin_W,    // [64][64]
    const float* __restrict__ lin_b,    // [64]
    const float* __restrict__ linUI_W,  // [64][64]
    const float* __restrict__ linUI_b,  // [64]
    float* __restrict__ out)            // [B][N][64]
{
    const int blk = blockIdx.x;   // = b*N_ + n, matches W_r/nghe/self leading dims
    const int b   = blk >> 3;
    const int t   = threadIdx.x;

    __shared__ float sU[S_][DIM_ + 1];   // nghu[b]       (pad 65: conflict-free)
    __shared__ float sE[S_][DIM_ + 1];   // nghe[b,n]
    __shared__ float sQ[S_][DIM_ + 1];   // q[b,n]
    __shared__ float sItem[DIM_];
    __shared__ float sWi[DIM_];
    __shared__ float sAtt[H_][S_];       // reused: user att, then entity att
    __shared__ float sUei[DIM_];         // user_ego[b]
    __shared__ float sTi[DIM_];          // item + user_ego
    __shared__ float sV[DIM_];           // v = signal * self
    __shared__ float sAgg[DIM_];

    // ---- stage nghu[b] and nghe[b,n] into LDS (float4 per thread each) ----
    {
        const int e0 = t * 4;            // 0..1023, covers 16*64 floats
        const int s  = e0 >> 6;
        const int c  = e0 & 63;
        float4 uu = *(const float4*)(nghu + (size_t)b * S_ * DIM_ + e0);
        sU[s][c + 0] = uu.x; sU[s][c + 1] = uu.y;
        sU[s][c + 2] = uu.z; sU[s][c + 3] = uu.w;
        float4 ee = *(const float4*)(nghe + (size_t)blk * S_ * DIM_ + e0);
        sE[s][c + 0] = ee.x; sE[s][c + 1] = ee.y;
        sE[s][c + 2] = ee.z; sE[s][c + 3] = ee.w;
        if (t < DIM_) sItem[t] = item_e[(size_t)b * DIM_ + t];
    }
    __syncthreads();

    // ---- Wi = W_ui @ item[b]  (wave0) ----
    if (t < DIM_) sWi[t] = dot_row64f(W_ui + t * DIM_, sItem);
    __syncthreads();

    // ---- user attention logits + softmax over S (wave0; lane = h*16+s) ----
    if (t < DIM_) {
        const int h = t >> 4, s = t & 15;
        float l = 0.f;
#pragma unroll
        for (int d = 0; d < DH_; ++d) l = fmaf(sWi[h * DH_ + d], sU[s][h * DH_ + d], l);
        l *= 0.25f;   // 1/sqrt(16)
        float mx = l;
#pragma unroll
        for (int off = 8; off; off >>= 1) mx = fmaxf(mx, __shfl_xor(mx, off, 16));
        float e = __expf(l - mx);
        float sm = e;
#pragma unroll
        for (int off = 8; off; off >>= 1) sm += __shfl_xor(sm, off, 16);
        sAtt[h][s] = e / sm;
    }
    __syncthreads();

    // ---- user_ego, item+ego ----
    if (t < DIM_) {
        const int h = t >> 4;
        float ego = 0.f;
#pragma unroll
        for (int s = 0; s < S_; ++s) ego = fmaf(sAtt[h][s], sU[s][t], ego);
        sUei[t] = ego;
        sTi[t]  = sItem[t] + ego;
    }
    __syncthreads();

    // ---- item_UI = relu(linUI_W @ (item+ego) + b); signal = user + item_UI; v = signal*self ----
    if (t < DIM_) {
        float a   = dot_row64f(linUI_W + t * DIM_, sTi) + linUI_b[t];
        float iui = fmaxf(a, 0.f);
        float sig = user_e[(size_t)b * DIM_ + t] + iui;
        sV[t] = sig * self_e[(size_t)blk * DIM_ + t];
    }
    __syncthreads();

    // ---- q[s,i] = W_r[b,n,s,i,:] . v   (all 256 threads, 4 rows each) ----
    {
        float v[DIM_];
#pragma unroll
        for (int j = 0; j < DIM_; ++j) v[j] = sV[j];
        const float* Wp = W_r + (size_t)blk * (S_ * DIM_ * DIM_);
#pragma unroll
        for (int k = 0; k < 4; ++k) {
            const int r = t + 256 * k;           // row = s*64 + i
            const float4* rp = (const float4*)(Wp + (size_t)r * DIM_);
            float acc = 0.f;
#pragma unroll
            for (int m = 0; m < 16; ++m) {
                float4 u = rp[m];
                acc = fmaf(u.x, v[4 * m + 0], acc);
                acc = fmaf(u.y, v[4 * m + 1], acc);
                acc = fmaf(u.z, v[4 * m + 2], acc);
                acc = fmaf(u.w, v[4 * m + 3], acc);
            }
            sQ[r >> 6][r & 63] = acc;
        }
    }
    __syncthreads();

    // ---- entity attention logits + softmax over S (wave0) ----
    if (t < DIM_) {
        const int h = t >> 4, s = t & 15;
        float l = 0.f;
#pragma unroll
        for (int d = 0; d < DH_; ++d) l = fmaf(sQ[s][h * DH_ + d], sE[s][h * DH_ + d], l);
        l *= 0.25f;
        float mx = l;
#pragma unroll
        for (int off = 8; off; off >>= 1) mx = fmaxf(mx, __shfl_xor(mx, off, 16));
        float e = __expf(l - mx);
        float sm = e;
#pragma unroll
        for (int off = 8; off; off >>= 1) sm += __shfl_xor(sm, off, 16);
        sAtt[h][s] = e / sm;
    }
    __syncthreads();

    // ---- entity_ego + aggregate ----
    if (t < DIM_) {
        const int h = t >> 4;
        float ego = 0.f;
#pragma unroll
        for (int s = 0; s < S_; ++s) ego = fmaf(sAtt[h][s], sE[s][t], ego);
        sAgg[t] = self_e[(size_t)blk * DIM_ + t] + sUei[t] + ego;
    }
    __syncthreads();

    // ---- out = relu(lin_W @ agg + lin_b) ----
    if (t < DIM_) {
        float o = dot_row64f(lin_W + t * DIM_, sAgg) + lin_b[t];
        o = fmaxf(o, 0.f);
        out[(size_t)blk * DIM_ + t] = o;
    }
}

extern "C" void kernel_launch(void* const* d_in, const int* in_sizes, int n_in,
                              void* d_out, int out_size, void* d_ws, size_t ws_size,
                              hipStream_t stream) {
    (void)in_sizes; (void)n_in; (void)d_ws; (void)ws_size; (void)out_size;
    const float* self_e  = (const float*)d_in[0];
    const float* nghu    = (const float*)d_in[1];
    const float* nghe    = (const float*)d_in[2];
    const float* user_e  = (const float*)d_in[3];
    const float* item_e  = (const float*)d_in[4];
    const float* W_r     = (const float*)d_in[5];
    const float* W_ui    = (const float*)d_in[6];
    const float* lin_W   = (const float*)d_in[7];
    const float* lin_b   = (const float*)d_in[8];
    const float* linUI_W = (const float*)d_in[9];
    const float* linUI_b = (const float*)d_in[10];
    // d_in[11] (is_item_layer) is constant 1 in the reference path.

    dim3 grid(B_ * N_);
    dim3 block(256);
    hipLaunchKernelGGL(EntityAggregator_63342177681721_kernel, grid, block, 0, stream,
                       self_e, nghu, nghe, user_e, item_e, W_r, W_ui,
                       lin_W, lin_b, linUI_W, linUI_b, (float*)d_out);
}

// Round 3
// 387.771 us; speedup vs baseline: 1.0726x; 1.0726x over previous
//
#include <hip/hip_runtime.h>
#include <hip/hip_bf16.h>

// Problem constants (B=128, N=8, S=16, DIM=64, H=4, DH=16)
#define B_   128
#define N_   8
#define S_   16
#define DIM_ 64
#define H_   4
#define DH_  16

// dot of a contiguous 64-elem fp32 row with a 64-elem fp32 vector (regs/LDS)
__device__ __forceinline__ float dot_row64f(const float* __restrict__ row,
                                            const float* __restrict__ v) {
    const float4* rp = (const float4*)row;
    float acc = 0.f;
#pragma unroll
    for (int m = 0; m < 16; ++m) {
        float4 u = rp[m];
        acc = fmaf(u.x, v[4 * m + 0], acc);
        acc = fmaf(u.y, v[4 * m + 1], acc);
        acc = fmaf(u.z, v[4 * m + 2], acc);
        acc = fmaf(u.w, v[4 * m + 3], acc);
    }
    return acc;
}

__global__ __launch_bounds__(256) void EntityAggregator_63342177681721_kernel(
    const float* __restrict__ self_e,   // [B][N][64]
    const float* __restrict__ nghu,     // [B][S][64]
    const float* __restrict__ nghe,     // [B][N][S][64]
    const float* __restrict__ user_e,   // [B][64]
    const float* __restrict__ item_e,   // [B][64]
    const float* __restrict__ W_r,      // [B][N][S][64][64]
    const float* __restrict__ W_ui,     // [64][64]
    const float* __restrict__ lin_W,    // [64][64]
    const float* __restrict__ lin_b,    // [64]
    const float* __restrict__ linUI_W,  // [64][64]
    const float* __restrict__ linUI_b,  // [64]
    float* __restrict__ out)            // [B][N][64]
{
    const int blk = blockIdx.x;   // = b*N_ + n, matches W_r/nghe/self leading dims
    const int b   = blk >> 3;
    const int t   = threadIdx.x;

    __shared__ float sU[S_][DIM_ + 1];   // nghu[b]       (pad 65: conflict-free)
    __shared__ float sE[S_][DIM_ + 1];   // nghe[b,n]
    __shared__ float sQ[S_][DIM_ + 1];   // q[b,n]
    __shared__ float sItem[DIM_];
    __shared__ float sWi[DIM_];
    __shared__ float sAtt[H_][S_];       // reused: user att, then entity att
    __shared__ float sUei[DIM_];         // user_ego[b]
    __shared__ float sTi[DIM_];          // item + user_ego
    __shared__ __align__(16) float sV[DIM_];  // v = signal * self (16B-aligned for float4 reads)
    __shared__ float sAgg[DIM_];

    // ---- stage nghu[b] and nghe[b,n] into LDS (float4 per thread each) ----
    {
        const int e0 = t * 4;            // 0..1023, covers 16*64 floats
        const int s  = e0 >> 6;
        const int c  = e0 & 63;
        float4 uu = *(const float4*)(nghu + (size_t)b * S_ * DIM_ + e0);
        sU[s][c + 0] = uu.x; sU[s][c + 1] = uu.y;
        sU[s][c + 2] = uu.z; sU[s][c + 3] = uu.w;
        float4 ee = *(const float4*)(nghe + (size_t)blk * S_ * DIM_ + e0);
        sE[s][c + 0] = ee.x; sE[s][c + 1] = ee.y;
        sE[s][c + 2] = ee.z; sE[s][c + 3] = ee.w;
        if (t < DIM_) sItem[t] = item_e[(size_t)b * DIM_ + t];
    }
    __syncthreads();

    // ---- Wi = W_ui @ item[b]  (wave0) ----
    if (t < DIM_) sWi[t] = dot_row64f(W_ui + t * DIM_, sItem);
    __syncthreads();

    // ---- user attention logits + softmax over S (wave0; lane = h*16+s) ----
    if (t < DIM_) {
        const int h = t >> 4, s = t & 15;
        float l = 0.f;
#pragma unroll
        for (int d = 0; d < DH_; ++d) l = fmaf(sWi[h * DH_ + d], sU[s][h * DH_ + d], l);
        l *= 0.25f;   // 1/sqrt(16)
        float mx = l;
#pragma unroll
        for (int off = 8; off; off >>= 1) mx = fmaxf(mx, __shfl_xor(mx, off, 16));
        float e = __expf(l - mx);
        float sm = e;
#pragma unroll
        for (int off = 8; off; off >>= 1) sm += __shfl_xor(sm, off, 16);
        sAtt[h][s] = e / sm;
    }
    __syncthreads();

    // ---- user_ego, item+ego ----
    if (t < DIM_) {
        const int h = t >> 4;
        float ego = 0.f;
#pragma unroll
        for (int s = 0; s < S_; ++s) ego = fmaf(sAtt[h][s], sU[s][t], ego);
        sUei[t] = ego;
        sTi[t]  = sItem[t] + ego;
    }
    __syncthreads();

    // ---- item_UI = relu(linUI_W @ (item+ego) + b); signal = user + item_UI; v = signal*self ----
    if (t < DIM_) {
        float a   = dot_row64f(linUI_W + t * DIM_, sTi) + linUI_b[t];
        float iui = fmaxf(a, 0.f);
        float sig = user_e[(size_t)b * DIM_ + t] + iui;
        sV[t] = sig * self_e[(size_t)blk * DIM_ + t];
    }
    __syncthreads();

    // ---- q[s,i] = W_r[b,n,s,i,:] . v ----
    // Coalesced layout: lane l of wave w handles segment seg=l&15 of row
    // row = w*256 + it*4 + (l>>4). One wave instruction = 64 consecutive
    // float4 = 1024 contiguous bytes (4 full rows). 16-lane shfl_xor reduce.
    {
        const int w   = t >> 6;          // wave id 0..3
        const int l   = t & 63;          // lane
        const int seg = l & 15;
        const int rg  = l >> 4;          // row-in-group 0..3
        const float4 v4 = ((const float4*)sV)[seg];
        // base float4 index for it=0: rows (w*256 .. w*256+3), lane l reads float4 #l
        const float4* p = (const float4*)(W_r + (size_t)blk * (S_ * DIM_ * DIM_))
                          + (size_t)w * 256 * 16 + l;
        int row0 = w * 256 + rg;
#pragma unroll 8
        for (int it = 0; it < 64; ++it) {
            float4 u = p[(size_t)it * 64];      // advance 4 rows (64 float4) per it
            float r = u.x * v4.x;
            r = fmaf(u.y, v4.y, r);
            r = fmaf(u.z, v4.z, r);
            r = fmaf(u.w, v4.w, r);
            r += __shfl_xor(r, 1);
            r += __shfl_xor(r, 2);
            r += __shfl_xor(r, 4);
            r += __shfl_xor(r, 8);
            if (seg == 0) {
                const int row = row0 + it * 4;  // = s*64 + i
                sQ[row >> 6][row & 63] = r;
            }
        }
    }
    __syncthreads();

    // ---- entity attention logits + softmax over S (wave0) ----
    if (t < DIM_) {
        const int h = t >> 4, s = t & 15;
        float l = 0.f;
#pragma unroll
        for (int d = 0; d < DH_; ++d) l = fmaf(sQ[s][h * DH_ + d], sE[s][h * DH_ + d], l);
        l *= 0.25f;
        float mx = l;
#pragma unroll
        for (int off = 8; off; off >>= 1) mx = fmaxf(mx, __shfl_xor(mx, off, 16));
        float e = __expf(l - mx);
        float sm = e;
#pragma unroll
        for (int off = 8; off; off >>= 1) sm += __shfl_xor(sm, off, 16);
        sAtt[h][s] = e / sm;
    }
    __syncthreads();

    // ---- entity_ego + aggregate ----
    if (t < DIM_) {
        const int h = t >> 4;
        float ego = 0.f;
#pragma unroll
        for (int s = 0; s < S_; ++s) ego = fmaf(sAtt[h][s], sE[s][t], ego);
        sAgg[t] = self_e[(size_t)blk * DIM_ + t] + sUei[t] + ego;
    }
    __syncthreads();

    // ---- out = relu(lin_W @ agg + lin_b) ----
    if (t < DIM_) {
        float o = dot_row64f(lin_W + t * DIM_, sAgg) + lin_b[t];
        o = fmaxf(o, 0.f);
        out[(size_t)blk * DIM_ + t] = o;
    }
}

extern "C" void kernel_launch(void* const* d_in, const int* in_sizes, int n_in,
                              void* d_out, int out_size, void* d_ws, size_t ws_size,
                              hipStream_t stream) {
    (void)in_sizes; (void)n_in; (void)d_ws; (void)ws_size; (void)out_size;
    const float* self_e  = (const float*)d_in[0];
    const float* nghu    = (const float*)d_in[1];
    const float* nghe    = (const float*)d_in[2];
    const float* user_e  = (const float*)d_in[3];
    const float* item_e  = (const float*)d_in[4];
    const float* W_r     = (const float*)d_in[5];
    const float* W_ui    = (const float*)d_in[6];
    const float* lin_W   = (const float*)d_in[7];
    const float* lin_b   = (const float*)d_in[8];
    const float* linUI_W = (const float*)d_in[9];
    const float* linUI_b = (const float*)d_in[10];

    dim3 grid(B_ * N_);
    dim3 block(256);
    hipLaunchKernelGGL(EntityAggregator_63342177681721_kernel, grid, block, 0, stream,
                       self_e, nghu, nghe, user_e, item_e, W_r, W_ui,
                       lin_W, lin_b, linUI_W, linUI_b, (float*)d_out);
}

// Round 5
// 380.632 us; speedup vs baseline: 1.0928x; 1.0188x over previous
//
#include <hip/hip_runtime.h>
#include <hip/hip_bf16.h>

// Problem constants (B=128, N=8, S=16, DIM=64, H=4, DH=16)
#define B_   128
#define N_   8
#define S_   16
#define DIM_ 64
#define H_   4
#define DH_  16

// dot of a contiguous 64-elem fp32 row with a 64-elem fp32 vector (regs/LDS)
__device__ __forceinline__ float dot_row64f(const float* __restrict__ row,
                                            const float* __restrict__ v) {
    const float4* rp = (const float4*)row;
    float acc = 0.f;
#pragma unroll
    for (int m = 0; m < 16; ++m) {
        float4 u = rp[m];
        acc = fmaf(u.x, v[4 * m + 0], acc);
        acc = fmaf(u.y, v[4 * m + 1], acc);
        acc = fmaf(u.z, v[4 * m + 2], acc);
        acc = fmaf(u.w, v[4 * m + 3], acc);
    }
    return acc;
}

// async global -> LDS, 16 bytes per lane; LDS dest = wave-uniform base + lane*16
__device__ __forceinline__ void load_lds16(const float* g, float* lds) {
    __builtin_amdgcn_global_load_lds(
        (const __attribute__((address_space(1))) void*)g,
        (__attribute__((address_space(3))) void*)lds,
        16, 0, 0);
}

__global__ __launch_bounds__(256) void EntityAggregator_63342177681721_kernel(
    const float* __restrict__ self_e,   // [B][N][64]
    const float* __restrict__ nghu,     // [B][S][64]
    const float* __restrict__ nghe,     // [B][N][S][64]
    const float* __restrict__ user_e,   // [B][64]
    const float* __restrict__ item_e,   // [B][64]
    const float* __restrict__ W_r,      // [B][N][S][64][64]
    const float* __restrict__ W_ui,     // [64][64]
    const float* __restrict__ lin_W,    // [64][64]
    const float* __restrict__ lin_b,    // [64]
    const float* __restrict__ linUI_W,  // [64][64]
    const float* __restrict__ linUI_b,  // [64]
    float* __restrict__ out)            // [B][N][64]
{
    const int blk  = blockIdx.x;   // = b*N_ + n
    const int b    = blk >> 3;
    const int t    = threadIdx.x;
    const int w    = t >> 6;       // wave 0..3
    const int lane = t & 63;

    // W_r double buffers: 2 x 128 rows x 64 floats = 2 x 32 KB
    __shared__ __align__(16) float sW0[128 * DIM_];
    __shared__ __align__(16) float sW1[128 * DIM_];
    __shared__ float sU[S_][DIM_ + 1];
    __shared__ float sE[S_][DIM_ + 1];
    __shared__ float sQ[S_][DIM_ + 1];
    __shared__ float sItem[DIM_];
    __shared__ float sWi[DIM_];
    __shared__ float sAtt[H_][S_];
    __shared__ float sUei[DIM_];
    __shared__ float sTi[DIM_];
    __shared__ __align__(16) float sV[DIM_];
    __shared__ float sAgg[DIM_];

    const float* Wp = W_r + (size_t)blk * (S_ * DIM_ * DIM_);  // 16384 floats

    // ---- kick off DMA of W_r chunks 0 and 1 immediately (independent of pre-phases)
    // chunk c = 128 rows = 8192 floats; per round: 4 waves x 1024B = 1024 floats
    {
        const float* g0 = Wp + w * 256 + lane * 4;
#pragma unroll
        for (int rr = 0; rr < 8; ++rr)
            load_lds16(g0 + rr * 1024, sW0 + w * 256 + rr * 1024);
        const float* g1 = Wp + 8192 + w * 256 + lane * 4;
#pragma unroll
        for (int rr = 0; rr < 8; ++rr)
            load_lds16(g1 + rr * 1024, sW1 + w * 256 + rr * 1024);
    }

    // ---- stage nghu[b] and nghe[b,n] into LDS ----
    {
        const int e0 = t * 4;
        const int s  = e0 >> 6;
        const int c  = e0 & 63;
        float4 uu = *(const float4*)(nghu + (size_t)b * S_ * DIM_ + e0);
        sU[s][c + 0] = uu.x; sU[s][c + 1] = uu.y;
        sU[s][c + 2] = uu.z; sU[s][c + 3] = uu.w;
        float4 ee = *(const float4*)(nghe + (size_t)blk * S_ * DIM_ + e0);
        sE[s][c + 0] = ee.x; sE[s][c + 1] = ee.y;
        sE[s][c + 2] = ee.z; sE[s][c + 3] = ee.w;
        if (t < DIM_) sItem[t] = item_e[(size_t)b * DIM_ + t];
    }
    __syncthreads();

    // ---- Wi = W_ui @ item[b] ----
    if (t < DIM_) sWi[t] = dot_row64f(W_ui + t * DIM_, sItem);
    __syncthreads();

    // ---- user attention softmax over S (wave0; lane = h*16+s) ----
    if (t < DIM_) {
        const int h = t >> 4, s = t & 15;
        float l = 0.f;
#pragma unroll
        for (int d = 0; d < DH_; ++d) l = fmaf(sWi[h * DH_ + d], sU[s][h * DH_ + d], l);
        l *= 0.25f;
        float mx = l;
#pragma unroll
        for (int off = 8; off; off >>= 1) mx = fmaxf(mx, __shfl_xor(mx, off, 16));
        float e = __expf(l - mx);
        float sm = e;
#pragma unroll
        for (int off = 8; off; off >>= 1) sm += __shfl_xor(sm, off, 16);
        sAtt[h][s] = e / sm;
    }
    __syncthreads();

    // ---- user_ego, item+ego ----
    if (t < DIM_) {
        const int h = t >> 4;
        float ego = 0.f;
#pragma unroll
        for (int s = 0; s < S_; ++s) ego = fmaf(sAtt[h][s], sU[s][t], ego);
        sUei[t] = ego;
        sTi[t]  = sItem[t] + ego;
    }
    __syncthreads();

    // ---- item_UI -> signal -> v ----
    if (t < DIM_) {
        float a   = dot_row64f(linUI_W + t * DIM_, sTi) + linUI_b[t];
        float iui = fmaxf(a, 0.f);
        float sig = user_e[(size_t)b * DIM_ + t] + iui;
        sV[t] = sig * self_e[(size_t)blk * DIM_ + t];
    }
    __syncthreads();   // drains DMA(0),DMA(1) too -> both chunks resident

    // ---- q[s,i] = W_r[b,n,s,i,:] . v : 8 chunks x 128 rows, double-buffered ----
    {
        const int  row  = t >> 1;     // 0..127
        const int  half = t & 1;      // which 32-float half of the row
        const float4* vv4 = (const float4*)sV;
#pragma unroll 1
        for (int c = 0; c < 8; ++c) {
            // prefetch chunk c+1 into the other buffer (chunks 0,1 pre-issued)
            if (c >= 1 && c < 7) {
                float* nb = ((c + 1) & 1) ? sW1 : sW0;
                const float* g = Wp + (size_t)(c + 1) * 8192 + w * 256 + lane * 4;
#pragma unroll
                for (int rr = 0; rr < 8; ++rr)
                    load_lds16(g + rr * 1024, nb + w * 256 + rr * 1024);
            }
            // compute chunk c
            const float4* bp = (const float4*)((c & 1) ? sW1 : sW0);
            float acc = 0.f;
#pragma unroll
            for (int m = 0; m < 8; ++m) {
                const int mm   = (m + row) & 7;       // rotate: spreads bank quads
                const int col4 = half * 8 + mm;
                float4 u = bp[row * 16 + col4];
                float4 v = vv4[col4];
                acc = fmaf(u.x, v.x, acc);
                acc = fmaf(u.y, v.y, acc);
                acc = fmaf(u.z, v.z, acc);
                acc = fmaf(u.w, v.w, acc);
            }
            acc += __shfl_xor(acc, 1);                // join the two half-rows
            if (half == 0) {
                const int rg = c * 128 + row;         // = s*64 + i
                sQ[rg >> 6][rg & 63] = acc;
            }
            __syncthreads();   // drains DMA(c+1); releases buf[c&1] for reuse
        }
    }

    // ---- entity attention softmax over S (wave0) ----
    if (t < DIM_) {
        const int h = t >> 4, s = t & 15;
        float l = 0.f;
#pragma unroll
        for (int d = 0; d < DH_; ++d) l = fmaf(sQ[s][h * DH_ + d], sE[s][h * DH_ + d], l);
        l *= 0.25f;
        float mx = l;
#pragma unroll
        for (int off = 8; off; off >>= 1) mx = fmaxf(mx, __shfl_xor(mx, off, 16));
        float e = __expf(l - mx);
        float sm = e;
#pragma unroll
        for (int off = 8; off; off >>= 1) sm += __shfl_xor(sm, off, 16);
        sAtt[h][s] = e / sm;
    }
    __syncthreads();

    // ---- entity_ego + aggregate ----
    if (t < DIM_) {
        const int h = t >> 4;
        float ego = 0.f;
#pragma unroll
        for (int s = 0; s < S_; ++s) ego = fmaf(sAtt[h][s], sE[s][t], ego);
        sAgg[t] = self_e[(size_t)blk * DIM_ + t] + sUei[t] + ego;
    }
    __syncthreads();

    // ---- out = relu(lin_W @ agg + lin_b) ----
    if (t < DIM_) {
        float o = dot_row64f(lin_W + t * DIM_, sAgg) + lin_b[t];
        o = fmaxf(o, 0.f);
        out[(size_t)blk * DIM_ + t] = o;
    }
}

extern "C" void kernel_launch(void* const* d_in, const int* in_sizes, int n_in,
                              void* d_out, int out_size, void* d_ws, size_t ws_size,
                              hipStream_t stream) {
    (void)in_sizes; (void)n_in; (void)d_ws; (void)ws_size; (void)out_size;
    const float* self_e  = (const float*)d_in[0];
    const float* nghu    = (const float*)d_in[1];
    const float* nghe    = (const float*)d_in[2];
    const float* user_e  = (const float*)d_in[3];
    const float* item_e  = (const float*)d_in[4];
    const float* W_r     = (const float*)d_in[5];
    const float* W_ui    = (const float*)d_in[6];
    const float* lin_W   = (const float*)d_in[7];
    const float* lin_b   = (const float*)d_in[8];
    const float* linUI_W = (const float*)d_in[9];
    const float* linUI_b = (const float*)d_in[10];

    dim3 grid(B_ * N_);
    dim3 block(256);
    hipLaunchKernelGGL(EntityAggregator_63342177681721_kernel, grid, block, 0, stream,
                       self_e, nghu, nghe, user_e, item_e, W_r, W_ui,
                       lin_W, lin_b, linUI_W, linUI_b, (float*)d_out);
}

// Round 6
// 380.488 us; speedup vs baseline: 1.0932x; 1.0004x over previous
//
#include <hip/hip_runtime.h>
#include <hip/hip_bf16.h>

// Problem constants (B=128, N=8, S=16, DIM=64, H=4, DH=16)
#define B_   128
#define N_   8
#define S_   16
#define DIM_ 64
#define H_   4
#define DH_  16

// dot of a contiguous 64-elem fp32 row with a 64-elem fp32 vector (regs/LDS)
__device__ __forceinline__ float dot_row64f(const float* __restrict__ row,
                                            const float* __restrict__ v) {
    const float4* rp = (const float4*)row;
    float acc = 0.f;
#pragma unroll
    for (int m = 0; m < 16; ++m) {
        float4 u = rp[m];
        acc = fmaf(u.x, v[4 * m + 0], acc);
        acc = fmaf(u.y, v[4 * m + 1], acc);
        acc = fmaf(u.z, v[4 * m + 2], acc);
        acc = fmaf(u.w, v[4 * m + 3], acc);
    }
    return acc;
}

// async global -> LDS, 16 bytes per lane; LDS dest = wave-uniform base + lane*16
__device__ __forceinline__ void load_lds16(const float* g, float* lds) {
    __builtin_amdgcn_global_load_lds(
        (const __attribute__((address_space(1))) void*)g,
        (__attribute__((address_space(3))) void*)lds,
        16, 0, 0);
}

__global__ __launch_bounds__(256) void EntityAggregator_63342177681721_kernel(
    const float* __restrict__ self_e,   // [B][N][64]
    const float* __restrict__ nghu,     // [B][S][64]
    const float* __restrict__ nghe,     // [B][N][S][64]
    const float* __restrict__ user_e,   // [B][64]
    const float* __restrict__ item_e,   // [B][64]
    const float* __restrict__ W_r,      // [B][N][S][64][64]
    const float* __restrict__ W_ui,     // [64][64]
    const float* __restrict__ lin_W,    // [64][64]
    const float* __restrict__ lin_b,    // [64]
    const float* __restrict__ linUI_W,  // [64][64]
    const float* __restrict__ linUI_b,  // [64]
    float* __restrict__ out)            // [B][N][64]
{
    const int blk  = blockIdx.x;   // = b*N_ + n
    const int b    = blk >> 3;
    const int t    = threadIdx.x;
    const int w    = t >> 6;       // wave 0..3
    const int lane = t & 63;

    // Per-wave W_r double buffers: 4 waves x 2 bufs x 2048 floats (8 KB) = 64 KB
    __shared__ __align__(16) float sW[4 * 2 * 2048];
    __shared__ float sU[S_][DIM_ + 1];
    __shared__ float sE[S_][DIM_ + 1];
    __shared__ float sQ[S_][DIM_ + 1];
    __shared__ float sItem[DIM_];
    __shared__ float sWi[DIM_];
    __shared__ float sAtt[H_][S_];
    __shared__ float sUei[DIM_];
    __shared__ float sTi[DIM_];
    __shared__ __align__(16) float sV[DIM_];
    __shared__ float sAgg[DIM_];

    const float* Wp = W_r + (size_t)blk * (S_ * DIM_ * DIM_);  // 65536 floats (256 KB)
    // Wave w owns floats [w*16384, (w+1)*16384) = rows [w*256, w*256+256).
    // Per-wave chunk = 2048 floats (32 rows, 8 KB) = 8 DMA instructions of 1 KB.

    // ---- pre-issue this wave's chunk 0 (completes during pre-phase barriers) ----
    {
        const float* g = Wp + w * 16384 + lane * 4;
        float* l = sW + (w << 1) * 2048;
#pragma unroll
        for (int rr = 0; rr < 8; ++rr)
            load_lds16(g + rr * 256, l + rr * 256);
    }

    // ---- stage nghu[b] and nghe[b,n] into LDS ----
    {
        const int e0 = t * 4;
        const int s  = e0 >> 6;
        const int c  = e0 & 63;
        float4 uu = *(const float4*)(nghu + (size_t)b * S_ * DIM_ + e0);
        sU[s][c + 0] = uu.x; sU[s][c + 1] = uu.y;
        sU[s][c + 2] = uu.z; sU[s][c + 3] = uu.w;
        float4 ee = *(const float4*)(nghe + (size_t)blk * S_ * DIM_ + e0);
        sE[s][c + 0] = ee.x; sE[s][c + 1] = ee.y;
        sE[s][c + 2] = ee.z; sE[s][c + 3] = ee.w;
        if (t < DIM_) sItem[t] = item_e[(size_t)b * DIM_ + t];
    }
    __syncthreads();

    // ---- Wi = W_ui @ item[b] ----
    if (t < DIM_) sWi[t] = dot_row64f(W_ui + t * DIM_, sItem);
    __syncthreads();

    // ---- user attention softmax over S (wave0; lane = h*16+s) ----
    if (t < DIM_) {
        const int h = t >> 4, s = t & 15;
        float l = 0.f;
#pragma unroll
        for (int d = 0; d < DH_; ++d) l = fmaf(sWi[h * DH_ + d], sU[s][h * DH_ + d], l);
        l *= 0.25f;
        float mx = l;
#pragma unroll
        for (int off = 8; off; off >>= 1) mx = fmaxf(mx, __shfl_xor(mx, off, 16));
        float e = __expf(l - mx);
        float sm = e;
#pragma unroll
        for (int off = 8; off; off >>= 1) sm += __shfl_xor(sm, off, 16);
        sAtt[h][s] = e / sm;
    }
    __syncthreads();

    // ---- user_ego, item+ego ----
    if (t < DIM_) {
        const int h = t >> 4;
        float ego = 0.f;
#pragma unroll
        for (int s = 0; s < S_; ++s) ego = fmaf(sAtt[h][s], sU[s][t], ego);
        sUei[t] = ego;
        sTi[t]  = sItem[t] + ego;
    }
    __syncthreads();

    // ---- item_UI -> signal -> v ----
    if (t < DIM_) {
        float a   = dot_row64f(linUI_W + t * DIM_, sTi) + linUI_b[t];
        float iui = fmaxf(a, 0.f);
        float sig = user_e[(size_t)b * DIM_ + t] + iui;
        sV[t] = sig * self_e[(size_t)blk * DIM_ + t];
    }
    __syncthreads();   // also drains chunk-0 DMA (vmcnt 0 at q-loop entry)

    // ---- q[s,i] = W_r[b,n,s,i,:] . v ----
    // Barrier-free pipelined loop: wave w produces AND consumes its own rows.
    // vmcnt is per-wave, so s_waitcnt vmcnt(8) orders chunk c's landing without
    // any __syncthreads (which would drain the prefetch and kill the pipeline).
    {
        const int r    = lane >> 1;   // 0..31: row within chunk
        const int half = lane & 1;    // which 32-float half of the row
        const float4* vv4 = (const float4*)sV;
#pragma unroll 1
        for (int c = 0; c < 8; ++c) {
            if (c < 7) {
                const float* g = Wp + w * 16384 + (c + 1) * 2048 + lane * 4;
                float* lb = sW + (((w << 1) | ((c + 1) & 1))) * 2048;
#pragma unroll
                for (int rr = 0; rr < 8; ++rr)
                    load_lds16(g + rr * 256, lb + rr * 256);
                asm volatile("s_waitcnt vmcnt(8)" ::: "memory");  // chunk c landed
            } else {
                asm volatile("s_waitcnt vmcnt(0)" ::: "memory");  // last chunk landed
            }
            const float4* bp = (const float4*)(sW + (((w << 1) | (c & 1))) * 2048);
            float acc = 0.f;
#pragma unroll
            for (int m = 0; m < 8; ++m) {
                const int col4 = half * 8 + ((m + r) & 7);  // rotate: 2-way banks only
                float4 u = bp[r * 16 + col4];
                float4 v = vv4[col4];
                acc = fmaf(u.x, v.x, acc);
                acc = fmaf(u.y, v.y, acc);
                acc = fmaf(u.z, v.z, acc);
                acc = fmaf(u.w, v.w, acc);
            }
            acc += __shfl_xor(acc, 1);                // join the two half-rows
            if (half == 0) {
                const int rowg = w * 256 + c * 32 + r;   // = s*64 + i
                sQ[rowg >> 6][rowg & 63] = acc;
            }
        }
    }
    __syncthreads();   // publish sQ across waves

    // ---- entity attention softmax over S (wave0) ----
    if (t < DIM_) {
        const int h = t >> 4, s = t & 15;
        float l = 0.f;
#pragma unroll
        for (int d = 0; d < DH_; ++d) l = fmaf(sQ[s][h * DH_ + d], sE[s][h * DH_ + d], l);
        l *= 0.25f;
        float mx = l;
#pragma unroll
        for (int off = 8; off; off >>= 1) mx = fmaxf(mx, __shfl_xor(mx, off, 16));
        float e = __expf(l - mx);
        float sm = e;
#pragma unroll
        for (int off = 8; off; off >>= 1) sm += __shfl_xor(sm, off, 16);
        sAtt[h][s] = e / sm;
    }
    __syncthreads();

    // ---- entity_ego + aggregate ----
    if (t < DIM_) {
        const int h = t >> 4;
        float ego = 0.f;
#pragma unroll
        for (int s = 0; s < S_; ++s) ego = fmaf(sAtt[h][s], sE[s][t], ego);
        sAgg[t] = self_e[(size_t)blk * DIM_ + t] + sUei[t] + ego;
    }
    __syncthreads();

    // ---- out = relu(lin_W @ agg + lin_b) ----
    if (t < DIM_) {
        float o = dot_row64f(lin_W + t * DIM_, sAgg) + lin_b[t];
        o = fmaxf(o, 0.f);
        out[(size_t)blk * DIM_ + t] = o;
    }
}

extern "C" void kernel_launch(void* const* d_in, const int* in_sizes, int n_in,
                              void* d_out, int out_size, void* d_ws, size_t ws_size,
                              hipStream_t stream) {
    (void)in_sizes; (void)n_in; (void)d_ws; (void)ws_size; (void)out_size;
    const float* self_e  = (const float*)d_in[0];
    const float* nghu    = (const float*)d_in[1];
    const float* nghe    = (const float*)d_in[2];
    const float* user_e  = (const float*)d_in[3];
    const float* item_e  = (const float*)d_in[4];
    const float* W_r     = (const float*)d_in[5];
    const float* W_ui    = (const float*)d_in[6];
    const float* lin_W   = (const float*)d_in[7];
    const float* lin_b   = (const float*)d_in[8];
    const float* linUI_W = (const float*)d_in[9];
    const float* linUI_b = (const float*)d_in[10];

    dim3 grid(B_ * N_);
    dim3 block(256);
    hipLaunchKernelGGL(EntityAggregator_63342177681721_kernel, grid, block, 0, stream,
                       self_e, nghu, nghe, user_e, item_e, W_r, W_ui,
                       lin_W, lin_b, linUI_W, linUI_b, (float*)d_out);
}